// Round 6
// baseline (509.636 us; speedup 1.0000x reference)
//
#include <hip/hip_runtime.h>
#include <stdint.h>
#include <type_traits>

// LlamaAttentionFused: RMSNorm -> QKV GEMM(+fused RoPE) -> Vtrans -> causal GQA flash attn -> O GEMM
// fp32 inputs/outputs; intermediates bf16; MFMA 16x16x32 bf16 with fp32 accumulation.
// R13: prep_k split into cast_k (grid-stride 2048 blocks, G11) + rms_k (2048 row-blocks).
//   Purpose: (a) per-stage dur becomes attributable in the dispatch table — top-5 currently
//   shows only QKV@107us, so prep/attn/O are each <106us but their split is unknown and
//   my floor model leaves ~120us unattributed; (b) grid-stride is the documented default
//   for memory-bound streaming (was 20480 tiny blocks).
//   GEMMs / vtrans / attn byte-identical to R12 (QKV: 937 TF, m97-structure ceiling).

typedef __bf16 bf16x8 __attribute__((ext_vector_type(8)));
typedef float f32x4 __attribute__((ext_vector_type(4)));

#define S_LEN 2048
#define HDIM 4096
#define QKV_N 6144
#define NQH 32
#define NKVH 8
#define HD 128

__device__ __forceinline__ float bf2f(uint16_t u){
    union { uint32_t u; float f; } v; v.u = ((uint32_t)u) << 16; return v.f;
}
__device__ __forceinline__ uint16_t f2bf(float f){
    union { float f; uint32_t u; } v; v.f = f;
    uint32_t u = v.u;
    return (uint16_t)((u + 0x7FFFu + ((u >> 16) & 1u)) >> 16);
}
__device__ __forceinline__ uint16_t f2bf_n(float f){   // native RTNE cvt (1 op)
    union { __bf16 b; uint16_t u; } v; v.b = (__bf16)f; return v.u;
}

// async global->LDS, 16B per lane. LDS dest must be wave_base + lane*16.
__device__ __forceinline__ void gload_lds16(uint16_t* lds_dst, const uint16_t* g_src){
    __builtin_amdgcn_global_load_lds(
        (const __attribute__((address_space(1))) void*)(g_src),
        (__attribute__((address_space(3))) void*)(lds_dst),
        16, 0, 0);
}

// ---------------- cast: wqkv | wo fp32->bf16, grid-strided ----------------
// 20480 chunks of 2048 elems: [0,12288) -> wqkv, [12288,20480) -> wo.
// 2048 blocks x 10 chunks each (grid-stride), 8 elems/thread/chunk.
__global__ __launch_bounds__(256) void cast_k(const float* __restrict__ w_qkv,
                                              const float* __restrict__ w_o,
                                              uint16_t* __restrict__ wqkv_b,
                                              uint16_t* __restrict__ wo_b){
    int t = threadIdx.x;
    for (int c = blockIdx.x; c < 20480; c += 2048){
        const float* src; uint16_t* dst; size_t i;
        if (c < 12288){ src = w_qkv; dst = wqkv_b; i = (size_t)c * 2048 + t * 8; }
        else          { src = w_o;   dst = wo_b;   i = (size_t)(c - 12288) * 2048 + t * 8; }
        float4 a = *(const float4*)(src + i);
        float4 d = *(const float4*)(src + i + 4);
        uint16_t o[8];
        o[0] = f2bf(a.x); o[1] = f2bf(a.y); o[2] = f2bf(a.z); o[3] = f2bf(a.w);
        o[4] = f2bf(d.x); o[5] = f2bf(d.y); o[6] = f2bf(d.z); o[7] = f2bf(d.w);
        *(uint4*)(dst + i) = *(uint4*)o;
    }
}

// ---------------- rms: rmsnorm row per block ----------------
__global__ __launch_bounds__(256) void rms_k(const float* __restrict__ x,
                                             const float* __restrict__ lw,
                                             uint16_t* __restrict__ xn){
    int row = blockIdx.x;
    int t = threadIdx.x;
    const float* xr = x + (size_t)row * HDIM + t * 16;
    float f[16];
#pragma unroll
    for (int p = 0; p < 4; ++p) *(float4*)(f + p * 4) = *(const float4*)(xr + p * 4);
    float ss = 0.f;
#pragma unroll
    for (int i = 0; i < 16; ++i) ss += f[i] * f[i];
#pragma unroll
    for (int off = 32; off > 0; off >>= 1) ss += __shfl_down(ss, off);
    __shared__ float red[4];
    if ((t & 63) == 0) red[t >> 6] = ss;
    __syncthreads();
    float tot = red[0] + red[1] + red[2] + red[3];
    float inv = rsqrtf(tot * (1.0f / HDIM) + 1e-5f);
    float wf[16];
#pragma unroll
    for (int p = 0; p < 4; ++p) *(float4*)(wf + p * 4) = *(const float4*)(lw + t * 16 + p * 4);
    uint16_t o[16];
#pragma unroll
    for (int i = 0; i < 16; ++i) o[i] = f2bf(f[i] * inv * wf[i]);
    uint16_t* outp = xn + (size_t)row * HDIM + t * 16;
    *(uint4*)(outp)     = *(uint4*)(o);
    *(uint4*)(outp + 8) = *(uint4*)(o + 8);
}

// ---------------- GEMM  C[M,N] = A[M,K] * B[N,K]^T (bf16 in, OutT out) -----
// 128x128 tile, BK=64, 4 waves. m97 structure (937 TF measured here; its ceiling).
// Wave column map (permuted for RoPE pair locality): col = wn*32 + (j&1)*16 + (j>>1)*64 + ln.
// ROPE=true (QKV): for q/k blocks (tileN < 5120) the epilogue rotates pairs
// (acc[i][jp], acc[i][jp+2]) = (x[d], x[d+64]) thread-locally in fp32, d = wn*32+jp*16+ln.
template <typename OutT, bool ROPE>
__global__ __launch_bounds__(256, 2) void gemm_bt_k(const uint16_t* __restrict__ A,
                                                    const uint16_t* __restrict__ B,
                                                    OutT* __restrict__ C,
                                                    int M, int N, int K,
                                                    const int* __restrict__ pos){
    __shared__ uint16_t lA[128 * 64];
    __shared__ uint16_t lB[128 * 64];
    int t = threadIdx.x;
    int lane = t & 63;
    int w = t >> 6;
    int wm = w >> 1, wn = w & 1;
    int quad = lane >> 4, ln = lane & 15;
    int tileM = blockIdx.y * 128, tileN = blockIdx.x * 128;

    f32x4 acc[4][4];
#pragma unroll
    for (int i = 0; i < 4; ++i)
#pragma unroll
      for (int j = 0; j < 4; ++j) acc[i][j] = (f32x4){0.f, 0.f, 0.f, 0.f};

    for (int k0 = 0; k0 < K; k0 += 64){
        __syncthreads();
#pragma unroll
        for (int it = 0; it < 4; ++it){
            int pp = it * 256 + t;          // chunk index, 8 bf16 per chunk
            int row = pp >> 3, cc = pp & 7;
            int gcc = cc ^ (row & 7);
            gload_lds16(&lA[pp * 8], A + (size_t)(tileM + row) * K + k0 + gcc * 8);
            gload_lds16(&lB[pp * 8], B + (size_t)(tileN + row) * K + k0 + gcc * 8);
        }
        __syncthreads();
#pragma unroll
        for (int kk = 0; kk < 64; kk += 32){
            int cc = (kk + quad * 8) >> 3;
            bf16x8 aF[4], bF[4];
#pragma unroll
            for (int i = 0; i < 4; ++i){
                int ra = wm * 64 + i * 16 + ln;
                aF[i] = *(const bf16x8*)&lA[ra * 64 + ((cc ^ (ra & 7)) * 8)];
                int rb = wn * 32 + (i & 1) * 16 + (i >> 1) * 64 + ln;   // permuted col map
                bF[i] = *(const bf16x8*)&lB[rb * 64 + ((cc ^ (rb & 7)) * 8)];
            }
#pragma unroll
            for (int i = 0; i < 4; ++i)
#pragma unroll
                for (int j = 0; j < 4; ++j)
                    acc[i][j] = __builtin_amdgcn_mfma_f32_16x16x32_bf16(aF[i], bF[j], acc[i][j], 0, 0, 0);
        }
    }
    // C/D layout: col(frag) = lane&15, row(frag) = quad*4 + reg (m89/m91 verified)
    if constexpr (ROPE){
        if (tileN < 5120){   // q or k head block (head-aligned: tileN % 128 == 0)
            // pair index d = wn*32 + jp*16 + ln (jp=0,1); partner at d+64 = acc[i][jp+2]
            const float c0 = -0.20762050593046014f;   // -log2(10000)/64
            float invf0 = exp2f((float)(wn * 32 + ln) * c0);
            float invf1 = exp2f((float)(wn * 32 + 16 + ln) * c0);
#pragma unroll
            for (int i = 0; i < 4; ++i)
#pragma unroll
              for (int r = 0; r < 4; ++r){
                  int row = tileM + wm * 64 + i * 16 + quad * 4 + r;
                  float fp = (float)pos[row];
#pragma unroll
                  for (int jp = 0; jp < 2; ++jp){
                      float sn, cs;
                      __sincosf(fp * (jp ? invf1 : invf0), &sn, &cs);
                      float x1 = acc[i][jp][r], x2 = acc[i][jp + 2][r];
                      int c1 = tileN + wn * 32 + jp * 16 + ln;
                      C[(size_t)row * N + c1]      = f2bf(x1 * cs - x2 * sn);
                      C[(size_t)row * N + c1 + 64] = f2bf(x2 * cs + x1 * sn);
                  }
              }
            return;
        }
    }
#pragma unroll
    for (int i = 0; i < 4; ++i)
#pragma unroll
      for (int r = 0; r < 4; ++r){
          int row = tileM + wm * 64 + i * 16 + quad * 4 + r;
#pragma unroll
          for (int j = 0; j < 4; ++j){
              int col = tileN + wn * 32 + (j & 1) * 16 + (j >> 1) * 64 + ln;
              if constexpr (std::is_same<OutT, float>::value)
                  C[(size_t)row * N + col] = acc[i][j][r];
              else
                  C[(size_t)row * N + col] = f2bf(acc[i][j][r]);
          }
      }
}

// ---------------- vtrans: V transpose only ----------
// 512 blocks: vT[c][s] = v[s][c], c = kvh*128+d (1024 rows), s (2048 cols)
__global__ __launch_bounds__(256) void vtrans_k(const uint16_t* __restrict__ qkv,
                                                uint16_t* __restrict__ vT){
    __shared__ uint16_t tile[64][65];
    int bx = blockIdx.x;
    int t = threadIdx.x;
    int ts = (bx & 31) * 64;
    int tc = (bx >> 5) * 64;
#pragma unroll
    for (int p = 0; p < 16; ++p){
        int lin = p * 256 + t;
        int r = lin >> 6, c = lin & 63;
        tile[r][c] = qkv[(size_t)(ts + r) * QKV_N + (HDIM + 1024) + tc + c];
    }
    __syncthreads();
#pragma unroll
    for (int p = 0; p < 16; ++p){
        int lin = p * 256 + t;
        int r = lin >> 6, c = lin & 63;
        vT[(size_t)(tc + r) * S_LEN + ts + c] = tile[c][r];
    }
}

// ---------------- Flash attention (causal, GQA group 4) ----------------
// block = (head h, 128 q rows); wave w owns 32 q rows. kv tiles of 64, double-buffered.
// exp2-domain softmax (Q pre-scaled by 1/sqrt(HD)*log2(e)); setprio around MFMA clusters.
// Waves fully above a kv tile skip its compute (uniform branch; STAGE + barrier still run).
__global__ __launch_bounds__(256, 2) void attn_k(const uint16_t* __restrict__ qkv,
                                                 const uint16_t* __restrict__ vT,
                                                 uint16_t* __restrict__ attn){
    __shared__ uint16_t lK[2][64 * 128];   // 2 x 16KB
    __shared__ uint16_t lV[2][64 * 128];   // 2 x 16KB (V^T tile: 128 d-rows x 64 s-cols)
    __shared__ uint16_t lP[4 * 2048];      // 16KB: wave-private 32x64 P regions
    int bid = blockIdx.x;
    int h = bid & 31;
    int z = bid >> 5;
    int qt = (z < 8) ? 15 - z : z - 8;   // heavy half first
    int kvh = h >> 2;
    int t = threadIdx.x, lane = t & 63, w = t >> 6;
    int quad = lane >> 4, ln = lane & 15;
    int qBase = qt * 128 + w * 32;

    // 1/sqrt(128) * log2(e): softmax computed in base-2 (v_exp_f32 is natively 2^x)
    const float scale = 0.1275174316788196f;

    bf16x8 qF[2][4];
#pragma unroll
    for (int i = 0; i < 2; ++i)
#pragma unroll
      for (int kk = 0; kk < 4; ++kk){
          int row = qBase + i * 16 + ln;
          bf16x8 raw = *(const bf16x8*)(qkv + (size_t)row * QKV_N + h * HD + kk * 32 + quad * 8);
#pragma unroll
          for (int e = 0; e < 8; ++e){
              union { __bf16 b; uint16_t u; } cv; cv.b = raw[e];
              union { uint16_t u; __bf16 b; } cw; cw.u = f2bf(bf2f(cv.u) * scale);
              raw[e] = cw.b;
          }
          qF[i][kk] = raw;
      }

    f32x4 oAcc[2][8];
#pragma unroll
    for (int i = 0; i < 2; ++i)
#pragma unroll
      for (int j = 0; j < 8; ++j) oAcc[i][j] = (f32x4){0.f, 0.f, 0.f, 0.f};
    float lsum[2][4];
#pragma unroll
    for (int i = 0; i < 2; ++i)
#pragma unroll
      for (int r = 0; r < 4; ++r) lsum[i][r] = 0.f;

    uint16_t* pB = lP + w * 2048;                // wave's 32x64 P region (4KB)

    int nkt = 2 * qt + 2;                        // kv tiles of 64

    #define STAGE(KT, B)                                                            \
    {                                                                               \
        _Pragma("unroll")                                                           \
        for (int it = 0; it < 4; ++it){                                             \
            int pp = it * 256 + t;                                                  \
            int row = pp >> 4, cc = pp & 15;                                        \
            int gcc = cc ^ (row & 7);                                               \
            gload_lds16(&lK[B][pp * 8],                                             \
                        qkv + (size_t)((KT) * 64 + row) * QKV_N + HDIM + kvh * HD + gcc * 8); \
            int rowv = pp >> 3, ccv = pp & 7;                                       \
            int gccv = ccv ^ (rowv & 7);                                            \
            gload_lds16(&lV[B][pp * 8],                                             \
                        vT + (size_t)(kvh * HD + rowv) * S_LEN + (KT) * 64 + gccv * 8); \
        }                                                                           \
    }

    STAGE(0, 0);
    __syncthreads();                              // buffer 0 staged (vmcnt drained)

    for (int kt = 0; kt < nkt; ++kt){
        int cur = kt & 1;
        if (kt + 1 < nkt) STAGE(kt + 1, cur ^ 1); // async prefetch; drained at loop-end barrier

        if (kt * 64 <= qBase + 31){               // skip tiles fully above the diagonal (wave-uniform)
            f32x4 sAcc[2][4];
#pragma unroll
            for (int i = 0; i < 2; ++i)
#pragma unroll
              for (int j = 0; j < 4; ++j) sAcc[i][j] = (f32x4){0.f, 0.f, 0.f, 0.f};

            __builtin_amdgcn_s_setprio(1);
#pragma unroll
            for (int kk = 0; kk < 4; ++kk){           // K-dim = HD = 128, steps of 32
                int cc = kk * 4 + quad;
                bf16x8 bF[4];
#pragma unroll
                for (int j = 0; j < 4; ++j){
                    int row = j * 16 + ln;
                    bF[j] = *(const bf16x8*)&lK[cur][row * 128 + ((cc ^ (row & 7)) * 8)];
                }
#pragma unroll
                for (int i = 0; i < 2; ++i)
#pragma unroll
                  for (int j = 0; j < 4; ++j)
                      sAcc[i][j] = __builtin_amdgcn_mfma_f32_16x16x32_bf16(qF[i][kk], bF[j], sAcc[i][j], 0, 0, 0);
            }
            __builtin_amdgcn_s_setprio(0);

            bool diag = (kt >= nkt - 2);              // last two tiles touch the diagonal band
#pragma unroll
            for (int i = 0; i < 2; ++i)
#pragma unroll
              for (int r = 0; r < 4; ++r){
                  int qrow = qBase + i * 16 + quad * 4 + r;
                  int prow = i * 16 + quad * 4 + r;
                  int pbase = prow * 64 + (ln & 7);
                  int bsel = ln >> 3, ssel = prow & 7;
                  float part = 0.f;
#pragma unroll
                  for (int j = 0; j < 4; ++j){
                      float sv = sAcc[i][j][r];
                      if (diag){
                          int colg = kt * 64 + j * 16 + ln;
                          if (colg > qrow) sv = -1e30f;   // exp2 -> 0
                      }
                      float pv = exp2f(sv);
                      part += pv;
                      pB[pbase + (((2 * j + bsel) ^ ssel) * 8)] = f2bf_n(pv);
                  }
                  lsum[i][r] += part;
              }

            __builtin_amdgcn_s_setprio(1);
#pragma unroll
            for (int kk = 0; kk < 2; ++kk){
                int cc = kk * 4 + quad;
                bf16x8 aP[2];
#pragma unroll
                for (int i = 0; i < 2; ++i){
                    int row = i * 16 + ln;
                    aP[i] = *(const bf16x8*)&pB[row * 64 + (((cc ^ (row & 7)) & 7) * 8)];
                }
                bf16x8 bV[8];
#pragma unroll
                for (int j = 0; j < 8; ++j){
                    int row = j * 16 + ln;
                    bV[j] = *(const bf16x8*)&lV[cur][row * 64 + (((cc ^ (row & 7)) & 7) * 8)];
                }
#pragma unroll
                for (int i = 0; i < 2; ++i)
#pragma unroll
                  for (int j = 0; j < 8; ++j)
                      oAcc[i][j] = __builtin_amdgcn_mfma_f32_16x16x32_bf16(aP[i], bV[j], oAcc[i][j], 0, 0, 0);
            }
            __builtin_amdgcn_s_setprio(0);
        }

        __syncthreads();   // drains this wave's prefetch + releases buffer cur
    }
    #undef STAGE

    // epilogue: finish the deferred row-sum reduction (16 lanes hold partials of a row)
#pragma unroll
    for (int i = 0; i < 2; ++i)
#pragma unroll
      for (int r = 0; r < 4; ++r){
          float l = lsum[i][r];
#pragma unroll
          for (int off = 1; off < 16; off <<= 1) l += __shfl_xor(l, off);
          float invl = 1.0f / l;
          int row = qBase + i * 16 + quad * 4 + r;
#pragma unroll
          for (int j = 0; j < 8; ++j)
              attn[(size_t)row * HDIM + h * HD + j * 16 + ln] = f2bf_n(oAcc[i][j][r] * invl);
      }
}

extern "C" void kernel_launch(void* const* d_in, const int* in_sizes, int n_in,
                              void* d_out, int out_size, void* d_ws, size_t ws_size,
                              hipStream_t stream){
    const int*   positions = (const int*)d_in[0];
    const float* hidden    = (const float*)d_in[1];
    const float* lw        = (const float*)d_in[2];
    const float* w_qkv     = (const float*)d_in[3];
    const float* w_o       = (const float*)d_in[4];
    float* out = (float*)d_out;

    // ws layout (bf16 elems): xn | qkv | vT | attn | wqkv_b | wo_b  (~147 MB)
    uint16_t* xn     = (uint16_t*)d_ws;
    uint16_t* qkv    = xn     + (size_t)S_LEN * HDIM;
    uint16_t* vT     = qkv    + (size_t)S_LEN * QKV_N;
    uint16_t* attn   = vT     + (size_t)NKVH * HD * S_LEN;
    uint16_t* wqkv_b = attn   + (size_t)S_LEN * HDIM;
    uint16_t* wo_b   = wqkv_b + (size_t)QKV_N * HDIM;

    cast_k<<<2048, 256, 0, stream>>>(w_qkv, w_o, wqkv_b, wo_b);
    rms_k<<<2048, 256, 0, stream>>>(hidden, lw, xn);
    gemm_bt_k<uint16_t, true><<<dim3(QKV_N / 128, S_LEN / 128), 256, 0, stream>>>(xn, wqkv_b, qkv, S_LEN, QKV_N, HDIM, positions);
    vtrans_k<<<512, 256, 0, stream>>>(qkv, vT);
    attn_k<<<NQH * (S_LEN / 128), 256, 0, stream>>>(qkv, vT, attn);
    gemm_bt_k<float, false><<<dim3(HDIM / 128, S_LEN / 128), 256, 0, stream>>>(attn, wo_b, out, S_LEN, HDIM, HDIM, positions);
}

// Round 8
// 461.654 us; speedup vs baseline: 1.1039x; 1.1039x over previous
//
#include <hip/hip_runtime.h>
#include <stdint.h>
#include <type_traits>

// LlamaAttentionFused: RMSNorm -> QKV GEMM(+fused RoPE, +wo-cast tail-fill) -> Vtrans ->
//                      causal GQA flash attn -> O GEMM
// fp32 inputs/outputs; intermediates bf16; MFMA 16x16x32 bf16 with fp32 accumulation.
// R15 == R14 resubmit (R14 bench was an infra failure: container died twice, no counters;
// kernel audited — no deadlock/OOB/divergence mechanism; same signature as R9's transient).
// R14: revert R13's grid-stride cast (regressed +29us). Structure = R12, plus:
//   - prep_k: wqkv cast [0,12288) + rms rows [12288,14336). One chunk/block (parallel shape).
//   - wo cast (8192 chunks) appended to the QKV GEMM grid (blocks >= 768): QKV runs 768
//     gemm blocks = 1.5 occupancy rounds at 2 blk/CU -> ~35us tail at 1 blk/CU; the
//     independent wo-cast blocks dispatch last and fill that tail (~16-25us serial cost
//     hidden). Ordering to O GEMM guaranteed by stream serialization.
//   - O GEMM: 512 gemm blocks exactly (2/CU, no tail), no cast blocks.
// GEMM inner loop / vtrans / attn byte-identical to R12 (QKV 937 TF = m97 ceiling).

typedef __bf16 bf16x8 __attribute__((ext_vector_type(8)));
typedef float f32x4 __attribute__((ext_vector_type(4)));

#define S_LEN 2048
#define HDIM 4096
#define QKV_N 6144
#define NQH 32
#define NKVH 8
#define HD 128

__device__ __forceinline__ float bf2f(uint16_t u){
    union { uint32_t u; float f; } v; v.u = ((uint32_t)u) << 16; return v.f;
}
__device__ __forceinline__ uint16_t f2bf(float f){
    union { float f; uint32_t u; } v; v.f = f;
    uint32_t u = v.u;
    return (uint16_t)((u + 0x7FFFu + ((u >> 16) & 1u)) >> 16);
}
__device__ __forceinline__ uint16_t f2bf_n(float f){   // native RTNE cvt (1 op)
    union { __bf16 b; uint16_t u; } v; v.b = (__bf16)f; return v.u;
}

// async global->LDS, 16B per lane. LDS dest must be wave_base + lane*16.
__device__ __forceinline__ void gload_lds16(uint16_t* lds_dst, const uint16_t* g_src){
    __builtin_amdgcn_global_load_lds(
        (const __attribute__((address_space(1))) void*)(g_src),
        (__attribute__((address_space(3))) void*)(lds_dst),
        16, 0, 0);
}

__device__ __forceinline__ void cast_chunk(const float* __restrict__ src,
                                           uint16_t* __restrict__ dst,
                                           int c, int t){
    size_t i = (size_t)c * 2048 + t * 8;
    float4 a = *(const float4*)(src + i);
    float4 d = *(const float4*)(src + i + 4);
    uint16_t o[8];
    o[0] = f2bf(a.x); o[1] = f2bf(a.y); o[2] = f2bf(a.z); o[3] = f2bf(a.w);
    o[4] = f2bf(d.x); o[5] = f2bf(d.y); o[6] = f2bf(d.z); o[7] = f2bf(d.w);
    *(uint4*)(dst + i) = *(uint4*)o;
}

// ---------------- prep: cast wqkv [0,12288) | rmsnorm rows [12288,14336) ----------
__global__ __launch_bounds__(256) void prep_k(const float* __restrict__ w_qkv,
                                              const float* __restrict__ x,
                                              const float* __restrict__ lw,
                                              uint16_t* __restrict__ wqkv_b,
                                              uint16_t* __restrict__ xn){
    int b = blockIdx.x;
    int t = threadIdx.x;
    if (b < 12288){
        cast_chunk(w_qkv, wqkv_b, b, t);
        return;
    }
    // rmsnorm
    int row = b - 12288;
    const float* xr = x + (size_t)row * HDIM + t * 16;
    float f[16];
#pragma unroll
    for (int p = 0; p < 4; ++p) *(float4*)(f + p * 4) = *(const float4*)(xr + p * 4);
    float ss = 0.f;
#pragma unroll
    for (int i = 0; i < 16; ++i) ss += f[i] * f[i];
#pragma unroll
    for (int off = 32; off > 0; off >>= 1) ss += __shfl_down(ss, off);
    __shared__ float red[4];
    if ((t & 63) == 0) red[t >> 6] = ss;
    __syncthreads();
    float tot = red[0] + red[1] + red[2] + red[3];
    float inv = rsqrtf(tot * (1.0f / HDIM) + 1e-5f);
    float wf[16];
#pragma unroll
    for (int p = 0; p < 4; ++p) *(float4*)(wf + p * 4) = *(const float4*)(lw + t * 16 + p * 4);
    uint16_t o[16];
#pragma unroll
    for (int i = 0; i < 16; ++i) o[i] = f2bf(f[i] * inv * wf[i]);
    uint16_t* outp = xn + (size_t)row * HDIM + t * 16;
    *(uint4*)(outp)     = *(uint4*)(o);
    *(uint4*)(outp + 8) = *(uint4*)(o + 8);
}

// ---------------- GEMM  C[M,N] = A[M,K] * B[N,K]^T (bf16 in, OutT out) -----
// 128x128 tile, BK=64, 4 waves. m97 structure (937 TF measured here; its ceiling).
// 1D grid: blocks [0, nbx*M/128) do GEMM (tileN = (b%nbx)*128, tileM = (b/nbx)*128);
// blocks >= gemmBlocks cast one 2048-elem chunk of castSrc (tail-fill; QKV launch only).
// Wave column map (permuted for RoPE pair locality): col = wn*32 + (j&1)*16 + (j>>1)*64 + ln.
// ROPE=true (QKV): for q/k blocks (tileN < 5120) the epilogue rotates pairs
// (acc[i][jp], acc[i][jp+2]) = (x[d], x[d+64]) thread-locally in fp32, d = wn*32+jp*16+ln.
template <typename OutT, bool ROPE>
__global__ __launch_bounds__(256, 2) void gemm_bt_k(const uint16_t* __restrict__ A,
                                                    const uint16_t* __restrict__ B,
                                                    OutT* __restrict__ C,
                                                    int M, int N, int K,
                                                    const int* __restrict__ pos,
                                                    int nbx,
                                                    const float* __restrict__ castSrc,
                                                    uint16_t* __restrict__ castDst){
    int b = blockIdx.x;
    int t = threadIdx.x;
    int gemmBlocks = nbx * (M >> 7);
    if (b >= gemmBlocks){                 // wo-cast tail-fill block
        cast_chunk(castSrc, castDst, b - gemmBlocks, t);
        return;
    }
    __shared__ uint16_t lA[128 * 64];
    __shared__ uint16_t lB[128 * 64];
    int lane = t & 63;
    int w = t >> 6;
    int wm = w >> 1, wn = w & 1;
    int quad = lane >> 4, ln = lane & 15;
    int tileM = (b / nbx) * 128, tileN = (b % nbx) * 128;

    f32x4 acc[4][4];
#pragma unroll
    for (int i = 0; i < 4; ++i)
#pragma unroll
      for (int j = 0; j < 4; ++j) acc[i][j] = (f32x4){0.f, 0.f, 0.f, 0.f};

    for (int k0 = 0; k0 < K; k0 += 64){
        __syncthreads();
#pragma unroll
        for (int it = 0; it < 4; ++it){
            int pp = it * 256 + t;          // chunk index, 8 bf16 per chunk
            int row = pp >> 3, cc = pp & 7;
            int gcc = cc ^ (row & 7);
            gload_lds16(&lA[pp * 8], A + (size_t)(tileM + row) * K + k0 + gcc * 8);
            gload_lds16(&lB[pp * 8], B + (size_t)(tileN + row) * K + k0 + gcc * 8);
        }
        __syncthreads();
#pragma unroll
        for (int kk = 0; kk < 64; kk += 32){
            int cc = (kk + quad * 8) >> 3;
            bf16x8 aF[4], bF[4];
#pragma unroll
            for (int i = 0; i < 4; ++i){
                int ra = wm * 64 + i * 16 + ln;
                aF[i] = *(const bf16x8*)&lA[ra * 64 + ((cc ^ (ra & 7)) * 8)];
                int rb = wn * 32 + (i & 1) * 16 + (i >> 1) * 64 + ln;   // permuted col map
                bF[i] = *(const bf16x8*)&lB[rb * 64 + ((cc ^ (rb & 7)) * 8)];
            }
#pragma unroll
            for (int i = 0; i < 4; ++i)
#pragma unroll
                for (int j = 0; j < 4; ++j)
                    acc[i][j] = __builtin_amdgcn_mfma_f32_16x16x32_bf16(aF[i], bF[j], acc[i][j], 0, 0, 0);
        }
    }
    // C/D layout: col(frag) = lane&15, row(frag) = quad*4 + reg (m89/m91 verified)
    if constexpr (ROPE){
        if (tileN < 5120){   // q or k head block (head-aligned: tileN % 128 == 0)
            // pair index d = wn*32 + jp*16 + ln (jp=0,1); partner at d+64 = acc[i][jp+2]
            const float c0 = -0.20762050593046014f;   // -log2(10000)/64
            float invf0 = exp2f((float)(wn * 32 + ln) * c0);
            float invf1 = exp2f((float)(wn * 32 + 16 + ln) * c0);
#pragma unroll
            for (int i = 0; i < 4; ++i)
#pragma unroll
              for (int r = 0; r < 4; ++r){
                  int row = tileM + wm * 64 + i * 16 + quad * 4 + r;
                  float fp = (float)pos[row];
#pragma unroll
                  for (int jp = 0; jp < 2; ++jp){
                      float sn, cs;
                      __sincosf(fp * (jp ? invf1 : invf0), &sn, &cs);
                      float x1 = acc[i][jp][r], x2 = acc[i][jp + 2][r];
                      int c1 = tileN + wn * 32 + jp * 16 + ln;
                      C[(size_t)row * N + c1]      = f2bf(x1 * cs - x2 * sn);
                      C[(size_t)row * N + c1 + 64] = f2bf(x2 * cs + x1 * sn);
                  }
              }
            return;
        }
    }
#pragma unroll
    for (int i = 0; i < 4; ++i)
#pragma unroll
      for (int r = 0; r < 4; ++r){
          int row = tileM + wm * 64 + i * 16 + quad * 4 + r;
#pragma unroll
          for (int j = 0; j < 4; ++j){
              int col = tileN + wn * 32 + (j & 1) * 16 + (j >> 1) * 64 + ln;
              if constexpr (std::is_same<OutT, float>::value)
                  C[(size_t)row * N + col] = acc[i][j][r];
              else
                  C[(size_t)row * N + col] = f2bf(acc[i][j][r]);
          }
      }
}

// ---------------- vtrans: V transpose only ----------
// 512 blocks: vT[c][s] = v[s][c], c = kvh*128+d (1024 rows), s (2048 cols)
__global__ __launch_bounds__(256) void vtrans_k(const uint16_t* __restrict__ qkv,
                                                uint16_t* __restrict__ vT){
    __shared__ uint16_t tile[64][65];
    int bx = blockIdx.x;
    int t = threadIdx.x;
    int ts = (bx & 31) * 64;
    int tc = (bx >> 5) * 64;
#pragma unroll
    for (int p = 0; p < 16; ++p){
        int lin = p * 256 + t;
        int r = lin >> 6, c = lin & 63;
        tile[r][c] = qkv[(size_t)(ts + r) * QKV_N + (HDIM + 1024) + tc + c];
    }
    __syncthreads();
#pragma unroll
    for (int p = 0; p < 16; ++p){
        int lin = p * 256 + t;
        int r = lin >> 6, c = lin & 63;
        vT[(size_t)(tc + r) * S_LEN + ts + c] = tile[c][r];
    }
}

// ---------------- Flash attention (causal, GQA group 4) ----------------
// block = (head h, 128 q rows); wave w owns 32 q rows. kv tiles of 64, double-buffered.
// exp2-domain softmax (Q pre-scaled by 1/sqrt(HD)*log2(e)); setprio around MFMA clusters.
// Waves fully above a kv tile skip its compute (uniform branch; STAGE + barrier still run).
__global__ __launch_bounds__(256, 2) void attn_k(const uint16_t* __restrict__ qkv,
                                                 const uint16_t* __restrict__ vT,
                                                 uint16_t* __restrict__ attn){
    __shared__ uint16_t lK[2][64 * 128];   // 2 x 16KB
    __shared__ uint16_t lV[2][64 * 128];   // 2 x 16KB (V^T tile: 128 d-rows x 64 s-cols)
    __shared__ uint16_t lP[4 * 2048];      // 16KB: wave-private 32x64 P regions
    int bid = blockIdx.x;
    int h = bid & 31;
    int z = bid >> 5;
    int qt = (z < 8) ? 15 - z : z - 8;   // heavy half first
    int kvh = h >> 2;
    int t = threadIdx.x, lane = t & 63, w = t >> 6;
    int quad = lane >> 4, ln = lane & 15;
    int qBase = qt * 128 + w * 32;

    // 1/sqrt(128) * log2(e): softmax computed in base-2 (v_exp_f32 is natively 2^x)
    const float scale = 0.1275174316788196f;

    bf16x8 qF[2][4];
#pragma unroll
    for (int i = 0; i < 2; ++i)
#pragma unroll
      for (int kk = 0; kk < 4; ++kk){
          int row = qBase + i * 16 + ln;
          bf16x8 raw = *(const bf16x8*)(qkv + (size_t)row * QKV_N + h * HD + kk * 32 + quad * 8);
#pragma unroll
          for (int e = 0; e < 8; ++e){
              union { __bf16 b; uint16_t u; } cv; cv.b = raw[e];
              union { uint16_t u; __bf16 b; } cw; cw.u = f2bf(bf2f(cv.u) * scale);
              raw[e] = cw.b;
          }
          qF[i][kk] = raw;
      }

    f32x4 oAcc[2][8];
#pragma unroll
    for (int i = 0; i < 2; ++i)
#pragma unroll
      for (int j = 0; j < 8; ++j) oAcc[i][j] = (f32x4){0.f, 0.f, 0.f, 0.f};
    float lsum[2][4];
#pragma unroll
    for (int i = 0; i < 2; ++i)
#pragma unroll
      for (int r = 0; r < 4; ++r) lsum[i][r] = 0.f;

    uint16_t* pB = lP + w * 2048;                // wave's 32x64 P region (4KB)

    int nkt = 2 * qt + 2;                        // kv tiles of 64

    #define STAGE(KT, B)                                                            \
    {                                                                               \
        _Pragma("unroll")                                                           \
        for (int it = 0; it < 4; ++it){                                             \
            int pp = it * 256 + t;                                                  \
            int row = pp >> 4, cc = pp & 15;                                        \
            int gcc = cc ^ (row & 7);                                               \
            gload_lds16(&lK[B][pp * 8],                                             \
                        qkv + (size_t)((KT) * 64 + row) * QKV_N + HDIM + kvh * HD + gcc * 8); \
            int rowv = pp >> 3, ccv = pp & 7;                                       \
            int gccv = ccv ^ (rowv & 7);                                            \
            gload_lds16(&lV[B][pp * 8],                                             \
                        vT + (size_t)(kvh * HD + rowv) * S_LEN + (KT) * 64 + gccv * 8); \
        }                                                                           \
    }

    STAGE(0, 0);
    __syncthreads();                              // buffer 0 staged (vmcnt drained)

    for (int kt = 0; kt < nkt; ++kt){
        int cur = kt & 1;
        if (kt + 1 < nkt) STAGE(kt + 1, cur ^ 1); // async prefetch; drained at loop-end barrier

        if (kt * 64 <= qBase + 31){               // skip tiles fully above the diagonal (wave-uniform)
            f32x4 sAcc[2][4];
#pragma unroll
            for (int i = 0; i < 2; ++i)
#pragma unroll
              for (int j = 0; j < 4; ++j) sAcc[i][j] = (f32x4){0.f, 0.f, 0.f, 0.f};

            __builtin_amdgcn_s_setprio(1);
#pragma unroll
            for (int kk = 0; kk < 4; ++kk){           // K-dim = HD = 128, steps of 32
                int cc = kk * 4 + quad;
                bf16x8 bF[4];
#pragma unroll
                for (int j = 0; j < 4; ++j){
                    int row = j * 16 + ln;
                    bF[j] = *(const bf16x8*)&lK[cur][row * 128 + ((cc ^ (row & 7)) * 8)];
                }
#pragma unroll
                for (int i = 0; i < 2; ++i)
#pragma unroll
                  for (int j = 0; j < 4; ++j)
                      sAcc[i][j] = __builtin_amdgcn_mfma_f32_16x16x32_bf16(qF[i][kk], bF[j], sAcc[i][j], 0, 0, 0);
            }
            __builtin_amdgcn_s_setprio(0);

            bool diag = (kt >= nkt - 2);              // last two tiles touch the diagonal band
#pragma unroll
            for (int i = 0; i < 2; ++i)
#pragma unroll
              for (int r = 0; r < 4; ++r){
                  int qrow = qBase + i * 16 + quad * 4 + r;
                  int prow = i * 16 + quad * 4 + r;
                  int pbase = prow * 64 + (ln & 7);
                  int bsel = ln >> 3, ssel = prow & 7;
                  float part = 0.f;
#pragma unroll
                  for (int j = 0; j < 4; ++j){
                      float sv = sAcc[i][j][r];
                      if (diag){
                          int colg = kt * 64 + j * 16 + ln;
                          if (colg > qrow) sv = -1e30f;   // exp2 -> 0
                      }
                      float pv = exp2f(sv);
                      part += pv;
                      pB[pbase + (((2 * j + bsel) ^ ssel) * 8)] = f2bf_n(pv);
                  }
                  lsum[i][r] += part;
              }

            __builtin_amdgcn_s_setprio(1);
#pragma unroll
            for (int kk = 0; kk < 2; ++kk){
                int cc = kk * 4 + quad;
                bf16x8 aP[2];
#pragma unroll
                for (int i = 0; i < 2; ++i){
                    int row = i * 16 + ln;
                    aP[i] = *(const bf16x8*)&pB[row * 64 + (((cc ^ (row & 7)) & 7) * 8)];
                }
                bf16x8 bV[8];
#pragma unroll
                for (int j = 0; j < 8; ++j){
                    int row = j * 16 + ln;
                    bV[j] = *(const bf16x8*)&lV[cur][row * 64 + (((cc ^ (row & 7)) & 7) * 8)];
                }
#pragma unroll
                for (int i = 0; i < 2; ++i)
#pragma unroll
                  for (int j = 0; j < 8; ++j)
                      oAcc[i][j] = __builtin_amdgcn_mfma_f32_16x16x32_bf16(aP[i], bV[j], oAcc[i][j], 0, 0, 0);
            }
            __builtin_amdgcn_s_setprio(0);
        }

        __syncthreads();   // drains this wave's prefetch + releases buffer cur
    }
    #undef STAGE

    // epilogue: finish the deferred row-sum reduction (16 lanes hold partials of a row)
#pragma unroll
    for (int i = 0; i < 2; ++i)
#pragma unroll
      for (int r = 0; r < 4; ++r){
          float l = lsum[i][r];
#pragma unroll
          for (int off = 1; off < 16; off <<= 1) l += __shfl_xor(l, off);
          float invl = 1.0f / l;
          int row = qBase + i * 16 + quad * 4 + r;
#pragma unroll
          for (int j = 0; j < 8; ++j)
              attn[(size_t)row * HDIM + h * HD + j * 16 + ln] = f2bf_n(oAcc[i][j][r] * invl);
      }
}

extern "C" void kernel_launch(void* const* d_in, const int* in_sizes, int n_in,
                              void* d_out, int out_size, void* d_ws, size_t ws_size,
                              hipStream_t stream){
    const int*   positions = (const int*)d_in[0];
    const float* hidden    = (const float*)d_in[1];
    const float* lw        = (const float*)d_in[2];
    const float* w_qkv     = (const float*)d_in[3];
    const float* w_o       = (const float*)d_in[4];
    float* out = (float*)d_out;

    // ws layout (bf16 elems): xn | qkv | vT | attn | wqkv_b | wo_b  (~147 MB)
    uint16_t* xn     = (uint16_t*)d_ws;
    uint16_t* qkv    = xn     + (size_t)S_LEN * HDIM;
    uint16_t* vT     = qkv    + (size_t)S_LEN * QKV_N;
    uint16_t* attn   = vT     + (size_t)NKVH * HD * S_LEN;
    uint16_t* wqkv_b = attn   + (size_t)S_LEN * HDIM;
    uint16_t* wo_b   = wqkv_b + (size_t)QKV_N * HDIM;

    prep_k<<<14336, 256, 0, stream>>>(w_qkv, hidden, lw, wqkv_b, xn);
    // QKV GEMM: 48x16 = 768 gemm blocks + 8192 wo-cast tail-fill blocks
    gemm_bt_k<uint16_t, true><<<768 + 8192, 256, 0, stream>>>(
        xn, wqkv_b, qkv, S_LEN, QKV_N, HDIM, positions, QKV_N / 128, w_o, wo_b);
    vtrans_k<<<512, 256, 0, stream>>>(qkv, vT);
    attn_k<<<NQH * (S_LEN / 128), 256, 0, stream>>>(qkv, vT, attn);
    // O GEMM: 32x16 = 512 gemm blocks, no cast tail
    gemm_bt_k<float, false><<<512, 256, 0, stream>>>(
        attn, wo_b, out, S_LEN, HDIM, HDIM, positions, HDIM / 128, nullptr, nullptr);
}